// Round 9
// baseline (122.129 us; speedup 1.0000x reference)
//
#include <hip/hip_runtime.h>
#include <hip/hip_fp16.h>
#include <math.h>

// Problem constants
#define NB 392      // n = b*oh*ow = 2*14*14
#define NI 288      // K*K*B = 9*32
#define NC 32       // C
#define NQ 16       // PSIZE
#define CQ 512      // NC*NQ
#define CH 544      // B*(PSIZE+1)
#define EPSV 1e-6f

// votes are fp8 e4m3 scaled by 32; scale folded into staged f16 weights
// (32 = 2^5, exact in f16 -> bitwise-identical products vs scaling after).
#define VSCALE 32.0f
#define VINV (1.0f / 32.0f)

// out layout (floats)
#define OFF_AOUT 200704       // NB*CQ
#define OFF_CAT  213248       // OFF_AOUT + NB*NC

#define RT_THREADS 512
#define RT_WAVES 8

typedef _Float16 v4h __attribute__((ext_vector_type(4)));
typedef float v4f __attribute__((ext_vector_type(4)));
typedef float v2f __attribute__((ext_vector_type(2)));

// dual-f32 FMA (VOP3P). NOT volatile: round-8 showed the chain latency, not
// the instruction count, limits routing -- let the scheduler interleave.
__device__ __forceinline__ v2f pk_fma(v2f a, v2f b, v2f c) {
    v2f d;
    asm("v_pk_fma_f32 %0, %1, %2, %3" : "=v"(d) : "v"(a), "v"(b), "v"(c));
    return d;
}

// ---------------------------------------------------------------------------
// Gather from x via the unfold channel-major reinterpret.
__device__ __forceinline__ float gather_x(const float* __restrict__ x, int n, int j) {
    int c_idx = j / 9;
    int rem = j - c_idx * 9;
    int ki = rem / 3;
    int kj = rem - ki * 3;
    int b_ = n / 196;
    int rest = n - b_ * 196;
    int yy = rest / 14;
    int xx = rest - yy * 14;
    int iy = yy + ki - 1;
    int ix = xx + kj - 1;
    float v = 0.f;
    if ((unsigned)iy < 14u && (unsigned)ix < 14u)
        v = x[((b_ * 14 + iy) * 14 + ix) * CH + c_idx];
    return v;
}

// ---------------------------------------------------------------------------
// votes via swapped-operand mfma 16x16x16 f16 (round-3 structure, measured
// ~22 us single-pass; WRITE 57.8 MB (floor ~9 us), VALUBusy 33%). Untouched.
__global__ __launch_bounds__(256) void votes_k(const float* __restrict__ x,
                                               const float* __restrict__ wts,
                                               uchar* __restrict__ votes) {
    __shared__ _Float16 wlds[8192];     // 16 KB swizzled f16 weights (x32)
    __shared__ uint tile[64 * 36];      // 9 KB, pitch 36 dwords (144 B)
    int mtt = blockIdx.x;         // 0..6
    int i = blockIdx.y;           // 0..287
    int t = threadIdx.x;
    int wv = t >> 6;
    int l = t & 63;
    int col = l & 15;
    int quad = l >> 4;

    // ---- stage wts[i] -> LDS (f16, x32, transposed, swizzled) ----
    const float* wsrc = wts + (size_t)i * 8192;
#pragma unroll
    for (int k = 0; k < 8; ++k) {
        int f0 = k * 1024 + t * 4;
        float4 w4 = *(const float4*)(wsrc + f0);
        int ct = f0 >> 8;
        int p = (f0 >> 4) & 15;
        int qd = p >> 2;
        int kk = p & 3;
        int q0 = f0 & 15;
        int s = (ct * 4 + qd) & 15;
        int base = ct * 256 + qd * 64 + kk;
        wlds[base + (((q0 + 0) ^ s) << 2)] = (_Float16)(w4.x * VSCALE);
        wlds[base + (((q0 + 1) ^ s) << 2)] = (_Float16)(w4.y * VSCALE);
        wlds[base + (((q0 + 2) ^ s) << 2)] = (_Float16)(w4.z * VSCALE);
        wlds[base + (((q0 + 3) ^ s) << 2)] = (_Float16)(w4.w * VSCALE);
    }

    // A-side p-frag: gather 4 p-values from x in-lane (n_row = col-mapped)
    int n_row = mtt * 64 + wv * 16 + col;
    v4h av = {};
    if (n_row < NB) {
        int jb = (i >> 5) * CH + (i & 31) * 16 + quad * 4;
#pragma unroll
        for (int kk = 0; kk < 4; ++kk)
            av[kk] = (_Float16)gather_x(x, n_row, jb + kk);
    }
    __syncthreads();

    const uchar* tileb = (const uchar*)tile;

    for (int ch = 0; ch < 4; ++ch) {
#pragma unroll
        for (int c8 = 0; c8 < 8; ++c8) {
            int ct = ch * 8 + c8;
            // bv: one conflict-free ds_read_b64 (weights pre-scaled x32)
            v4h bv = *(const v4h*)&wlds[ct * 256 + quad * 64 +
                                        ((col ^ ((ct * 4 + quad) & 15)) << 2)];
            v4f acc = {0.f, 0.f, 0.f, 0.f};
            acc = __builtin_amdgcn_mfma_f32_16x16x16f16(bv, av, acc, 0, 0, 0);
            // lane holds votes[n=...+col][cq = ct*16 + quad*4 + 0..3]
            uint u = __builtin_amdgcn_cvt_pk_fp8_f32(acc[0], acc[1], 0, false);
            u = __builtin_amdgcn_cvt_pk_fp8_f32(acc[2], acc[3], u, true);
            tile[(wv * 16 + col) * 36 + c8 * 4 + quad] = u;
        }
        __syncthreads();
        // 64 rows x 8 uint4 = 512 uint4; 2 steps; 8 lanes store a row's 128 B.
#pragma unroll
        for (int k = 0; k < 2; ++k) {
            int idx = k * 256 + t;
            int row = idx >> 3;
            int off = idx & 7;
            int n_out = mtt * 64 + row;
            if (n_out < NB) {
                uint4 d = *(const uint4*)&tileb[row * 144 + off * 16];
                *(uint4*)(votes + (((size_t)n_out * NI + i) << 9) + ch * 128 + off * 16) = d;
            }
        }
        __syncthreads();
    }
}

// ---------------------------------------------------------------------------
// Fused dynamic routing. ROUND-9: routing is LATENCY-bound (round-8: halving
// FMA count moved nothing; VALUBusy 44% at ~2-3 waves/SIMD). This round runs
// TWO i-rows per step (9 steps x 2) with fully independent register state
// (vtA/vtB, sregA/sregB, two dot->exp->shfl chains) so the dependent chains
// overlap in-thread (ILP 2), plus split-4 dot trees (chain 8 -> 4 deep).
// i mapping: group grp = wv*2+g (0..15); iA = (2s)*16+grp, iB = (2s+1)*16+grp.
// s_j accumulation: (sum of even steps) + (sum of odd steps) -- f32 reorder,
// ~1e-6 scale vs the fp8-dominated 1.7e-3 absmax.
__global__ __launch_bounds__(RT_THREADS) void routing_k(const uchar* __restrict__ votes,
                                                        const float* __restrict__ x,
                                                        float* __restrict__ out) {
    __shared__ float afs[NI];
    __shared__ float sred[RT_WAVES * CQ];   // 16 KB, [group][q*32+c]
    __shared__ float vj[CQ];                // [q*32+c]
    __shared__ float aout_s[NC];

    int n = blockIdx.x;
    int t = threadIdx.x;
    int wv = t >> 6;      // 0..7
    int l = t & 63;
    int c = l & 31;
    int g = l >> 5;
    int grp = (wv << 1) | g;   // 0..15

    if (t < NI) {
        int j = (t >> 5) * CH + 512 + (t & 31);
        float v = gather_x(x, n, j);
        float a = fminf(fmaxf(v, 1e-4f), 1.0f);
        afs[t] = a / (a + EPSV);
    }
    __syncthreads();

    const uchar* vb = votes + (size_t)n * NI * 512;
    v2f vjr2[8];    // cumulative vj pairs, PRE-SCALED by 1/32

#define VROW(S) (((const uint4*)(vb + ((size_t)(((S) << 4) + grp) << 9)))[c])

#define DECODE2(CUR, VT) { \
    VT[0] = __builtin_amdgcn_cvt_pk_f32_fp8(CUR.x, false); \
    VT[1] = __builtin_amdgcn_cvt_pk_f32_fp8(CUR.x, true);  \
    VT[2] = __builtin_amdgcn_cvt_pk_f32_fp8(CUR.y, false); \
    VT[3] = __builtin_amdgcn_cvt_pk_f32_fp8(CUR.y, true);  \
    VT[4] = __builtin_amdgcn_cvt_pk_f32_fp8(CUR.z, false); \
    VT[5] = __builtin_amdgcn_cvt_pk_f32_fp8(CUR.z, true);  \
    VT[6] = __builtin_amdgcn_cvt_pk_f32_fp8(CUR.w, false); \
    VT[7] = __builtin_amdgcn_cvt_pk_f32_fp8(CUR.w, true);  }

    for (int iter = 0; iter < 3; ++iter) {
        v2f sregA[8], sregB[8];
#pragma unroll
        for (int j = 0; j < 8; ++j) {
            sregA[j] = (v2f){0.f, 0.f};
            sregB[j] = (v2f){0.f, 0.f};
        }

        // prefetch 2 steps ahead (4 rows)
        uint4 fA0 = VROW(0), fB0 = VROW(1), fA1 = VROW(2), fB1 = VROW(3);

        for (int s = 0; s < 9; ++s) {
            int iA = (s << 5) + grp;          // (2s)*16 + grp
            int iB = (s << 5) + 16 + grp;     // (2s+1)*16 + grp
            uint4 curA = fA0, curB = fB0;
            fA0 = fA1; fB0 = fB1;
            if (s + 2 < 9) {
                fA1 = VROW(2 * s + 4);
                fB1 = VROW(2 * s + 5);
            }

            v2f vtA[8], vtB[8];
            DECODE2(curA, vtA);
            DECODE2(curB, vtB);

            float cijA, cijB;
            if (iter == 0) {
                cijA = afs[iA] * (1.0f / 32.0f);
                cijB = afs[iB] * (1.0f / 32.0f);
            } else {
                // two independent split-4 dot trees (A and B interleave)
                v2f aX = {0.f, 0.f}, aY = {0.f, 0.f};
                v2f bX = {0.f, 0.f}, bY = {0.f, 0.f};
#pragma unroll
                for (int j = 0; j < 4; ++j) {
                    aX = pk_fma(vtA[j], vjr2[j], aX);
                    bX = pk_fma(vtB[j], vjr2[j], bX);
                    aY = pk_fma(vtA[j + 4], vjr2[j + 4], aY);
                    bY = pk_fma(vtB[j + 4], vjr2[j + 4], bY);
                }
                v2f aS = aX + aY, bS = bX + bY;
                float ahA = aS[0] + aS[1];
                float ahB = bS[0] + bS[1];
                float eA = __expf(ahA);
                float eB = __expf(ahB);
                float sA = eA, sB = eB;
                sA += __shfl_xor(sA, 1);  sB += __shfl_xor(sB, 1);
                sA += __shfl_xor(sA, 2);  sB += __shfl_xor(sB, 2);
                sA += __shfl_xor(sA, 4);  sB += __shfl_xor(sB, 4);
                sA += __shfl_xor(sA, 8);  sB += __shfl_xor(sB, 8);
                sA += __shfl_xor(sA, 16); sB += __shfl_xor(sB, 16);
                cijA = eA * __builtin_amdgcn_rcpf(sA) * afs[iA];
                cijB = eB * __builtin_amdgcn_rcpf(sB) * afs[iB];
            }
            v2f cA2 = {cijA, cijA}, cB2 = {cijB, cijB};
#pragma unroll
            for (int j = 0; j < 8; ++j) {
                sregA[j] = pk_fma(cA2, vtA[j], sregA[j]);
                sregB[j] = pk_fma(cB2, vtB[j], sregB[j]);
            }
        }

        // merge A/B, fold g-halves, write partials (layout [q*32+c]: bank==c)
        v2f sreg2[8];
#pragma unroll
        for (int j = 0; j < 8; ++j) {
            sreg2[j] = sregA[j] + sregB[j];
            v2f o;
            o[0] = __shfl_xor(sreg2[j][0], 32);
            o[1] = __shfl_xor(sreg2[j][1], 32);
            sreg2[j] += o;
        }
        if (g == 0) {
            float* sw = &sred[wv * CQ + c];
#pragma unroll
            for (int j = 0; j < 8; ++j) {
                sw[(2 * j) * 32] = sreg2[j][0];
                sw[(2 * j + 1) * 32] = sreg2[j][1];
            }
        }
        __syncthreads();
        {
            float ssum = 0.f;   // 512 threads == CQ columns
#pragma unroll
            for (int k = 0; k < RT_WAVES; ++k) ssum += sred[k * CQ + t];
            sred[t] = ssum * VINV;   // descale the x32 fp8 encoding ONCE
        }
        __syncthreads();

        // squash (threads 0..31, one c each; element (c,q) at sred[q*32+c])
        if (t < NC) {
            float s2 = 0.f;
#pragma unroll
            for (int q = 0; q < 16; ++q) {
                float s = sred[q * 32 + t];
                s2 += s * s;
            }
            float f = (s2 / (1.f + s2)) / sqrtf(s2 + EPSV);
            float vn2 = 0.f;
#pragma unroll
            for (int q = 0; q < 16; ++q) {
                float v = f * sred[q * 32 + t];
                vj[q * 32 + t] = v;
                vn2 += v * v;
            }
            if (iter == 2) {
                float ao = sqrtf(vn2 + EPSV);
                ao = fminf(fmaxf(ao, 1e-4f), 1.f - 1e-4f);
                aout_s[t] = ao;
            }
        }
        __syncthreads();
        if (iter < 2) {
#pragma unroll
            for (int j = 0; j < 8; ++j) {
                v2f nv;
                nv[0] = vj[(2 * j) * 32 + c] * VINV;       // pre-scale for raw dot
                nv[1] = vj[(2 * j + 1) * 32 + c] * VINV;
                vjr2[j] = (iter == 0) ? nv : vjr2[j] + nv;
            }
        }
    }

    // outputs: p_out, a_out, concat(out).  canonical idx t: c=t>>4, q=t&15
    {
        float v = vj[(t & 15) * 32 + (t >> 4)];
        out[(size_t)n * CQ + t] = v;
        out[OFF_CAT + (size_t)n * 544 + t] = v;
    }
    if (t < NC) {
        float ao = aout_s[t];
        out[OFF_AOUT + n * 32 + t] = ao;
        out[OFF_CAT + (size_t)n * 544 + 512 + t] = ao;
    }
}

// ---------------------------------------------------------------------------
extern "C" void kernel_launch(void* const* d_in, const int* in_sizes, int n_in,
                              void* d_out, int out_size, void* d_ws, size_t ws_size,
                              hipStream_t stream) {
    const float* x = (const float*)d_in[0];
    const float* wts = (const float*)d_in[1];
    float* out = (float*)d_out;
    uchar* votes = (uchar*)d_ws;   // 57.8 MB fp8

    hipLaunchKernelGGL(votes_k, dim3(7, NI), dim3(256), 0, stream,
                       x, wts, votes);
    hipLaunchKernelGGL(routing_k, dim3(NB), dim3(RT_THREADS), 0, stream,
                       votes, x, out);
}

// Round 10
// 118.688 us; speedup vs baseline: 1.0290x; 1.0290x over previous
//
#include <hip/hip_runtime.h>
#include <hip/hip_fp16.h>
#include <math.h>

// Problem constants
#define NB 392      // n = b*oh*ow = 2*14*14
#define NI 288      // K*K*B = 9*32
#define NC 32       // C
#define NQ 16       // PSIZE
#define CQ 512      // NC*NQ
#define CH 544      // B*(PSIZE+1)
#define EPSV 1e-6f

// votes are fp8 e4m3 scaled by 32; scale folded into staged f16 weights
// (32 = 2^5, exact in f16 -> bitwise-identical products vs scaling after).
#define VSCALE 32.0f
#define VINV (1.0f / 32.0f)

// out layout (floats)
#define OFF_AOUT 200704       // NB*CQ
#define OFF_CAT  213248       // OFF_AOUT + NB*NC

#define RT_THREADS 512
#define RT_WAVES 8

// workspace layout: votes at 0 (57.8 MB); p16 at +64 MiB (3.6 MB f16)
#define P16_OFF (64u << 20)
#define NP16 (NI * 16 * NB)   // 1,806,336 f16 values

typedef _Float16 v4h __attribute__((ext_vector_type(4)));
typedef float v4f __attribute__((ext_vector_type(4)));
typedef float v2f __attribute__((ext_vector_type(2)));

// dual-f32 FMA (VOP3P); round-8 measured win, kept.
__device__ __forceinline__ v2f pk_fma(v2f a, v2f b, v2f c) {
    v2f d;
    asm volatile("v_pk_fma_f32 %0, %1, %2, %3" : "=v"(d) : "v"(a), "v"(b), "v"(c));
    return d;
}

// ---------------------------------------------------------------------------
// Gather from x via the unfold channel-major reinterpret.
__device__ __forceinline__ float gather_x(const float* __restrict__ x, int n, int j) {
    int c_idx = j / 9;
    int rem = j - c_idx * 9;
    int ki = rem / 3;
    int kj = rem - ki * 3;
    int b_ = n / 196;
    int rest = n - b_ * 196;
    int yy = rest / 14;
    int xx = rest - yy * 14;
    int iy = yy + ki - 1;
    int ix = xx + kj - 1;
    float v = 0.f;
    if ((unsigned)iy < 14u && (unsigned)ix < 14u)
        v = x[((b_ * 14 + iy) * 14 + ix) * CH + c_idx];
    return v;
}

// ---------------------------------------------------------------------------
// ROUND-10: materialize the A-side p-values once as f16, layout [i][e][n]
// (n fastest -> votes_k's 16-lane col groups read 32 B contiguous runs).
// Value path identical to the old in-votes gather ((_Float16)gather_x) ->
// bit-identical votes. 3.6 MB, L3-resident.
__global__ __launch_bounds__(256) void prep_k(const float* __restrict__ x,
                                              _Float16* __restrict__ p16) {
    int idx = blockIdx.x * 256 + threadIdx.x;
    if (idx >= NP16) return;
    int n = idx % NB;
    int ie = idx / NB;            // i*16 + e
    int i = ie >> 4;
    int e = ie & 15;
    int j = (i >> 5) * CH + (i & 31) * 16 + e;
    p16[idx] = (_Float16)gather_x(x, n, j);
}

// ---------------------------------------------------------------------------
// votes via swapped-operand mfma 16x16x16 f16 (round-3 structure). ROUND-10
// change: A-frag reads 4 pre-gathered f16 from p16 (coalesced-in-n) instead
// of 4 scalar x-gathers with ~30 VALU of index math each -- the suspected
// stall source (votes_k was 22us at VALUBusy 33%, HBM 52%, MfmaUtil 6.7%).
__global__ __launch_bounds__(256) void votes_k(const float* __restrict__ wts,
                                               const _Float16* __restrict__ p16,
                                               uchar* __restrict__ votes) {
    __shared__ _Float16 wlds[8192];     // 16 KB swizzled f16 weights (x32)
    __shared__ uint tile[64 * 36];      // 9 KB, pitch 36 dwords (144 B)
    int mtt = blockIdx.x;         // 0..6
    int i = blockIdx.y;           // 0..287
    int t = threadIdx.x;
    int wv = t >> 6;
    int l = t & 63;
    int col = l & 15;
    int quad = l >> 4;

    // ---- stage wts[i] -> LDS (f16, x32, transposed, swizzled) ----
    const float* wsrc = wts + (size_t)i * 8192;
#pragma unroll
    for (int k = 0; k < 8; ++k) {
        int f0 = k * 1024 + t * 4;
        float4 w4 = *(const float4*)(wsrc + f0);
        int ct = f0 >> 8;
        int p = (f0 >> 4) & 15;
        int qd = p >> 2;
        int kk = p & 3;
        int q0 = f0 & 15;
        int s = (ct * 4 + qd) & 15;
        int base = ct * 256 + qd * 64 + kk;
        wlds[base + (((q0 + 0) ^ s) << 2)] = (_Float16)(w4.x * VSCALE);
        wlds[base + (((q0 + 1) ^ s) << 2)] = (_Float16)(w4.y * VSCALE);
        wlds[base + (((q0 + 2) ^ s) << 2)] = (_Float16)(w4.z * VSCALE);
        wlds[base + (((q0 + 3) ^ s) << 2)] = (_Float16)(w4.w * VSCALE);
    }

    // A-side p-frag: 4 f16 loads from p16[i][quad*4+kk][n_row]
    int n_row = mtt * 64 + wv * 16 + col;
    v4h av = {};
    if (n_row < NB) {
        const _Float16* pb = p16 + ((size_t)i * 16 + quad * 4) * NB + n_row;
#pragma unroll
        for (int kk = 0; kk < 4; ++kk)
            av[kk] = pb[kk * NB];
    }
    __syncthreads();

    const uchar* tileb = (const uchar*)tile;

    for (int ch = 0; ch < 4; ++ch) {
#pragma unroll
        for (int c8 = 0; c8 < 8; ++c8) {
            int ct = ch * 8 + c8;
            // bv: one conflict-free ds_read_b64 (weights pre-scaled x32)
            v4h bv = *(const v4h*)&wlds[ct * 256 + quad * 64 +
                                        ((col ^ ((ct * 4 + quad) & 15)) << 2)];
            v4f acc = {0.f, 0.f, 0.f, 0.f};
            acc = __builtin_amdgcn_mfma_f32_16x16x16f16(bv, av, acc, 0, 0, 0);
            // lane holds votes[n=...+col][cq = ct*16 + quad*4 + 0..3]
            uint u = __builtin_amdgcn_cvt_pk_fp8_f32(acc[0], acc[1], 0, false);
            u = __builtin_amdgcn_cvt_pk_fp8_f32(acc[2], acc[3], u, true);
            tile[(wv * 16 + col) * 36 + c8 * 4 + quad] = u;
        }
        __syncthreads();
        // 64 rows x 8 uint4 = 512 uint4; 2 steps; 8 lanes store a row's 128 B.
#pragma unroll
        for (int k = 0; k < 2; ++k) {
            int idx = k * 256 + t;
            int row = idx >> 3;
            int off = idx & 7;
            int n_out = mtt * 64 + row;
            if (n_out < NB) {
                uint4 d = *(const uint4*)&tileb[row * 144 + off * 16];
                *(uint4*)(votes + (((size_t)n_out * NI + i) << 9) + ch * 128 + off * 16) = d;
            }
        }
        __syncthreads();
    }
}

// ---------------------------------------------------------------------------
// Fused dynamic routing — ROUND-8 form verbatim (best measured: packed-f32
// inner math, 18 steps, depth-4 prefetch). Round-9's ILP-2 variant regressed
// (VGPR allocator chose 68 -> prefetch distance destroyed, VALUBusy 44->19%).
__global__ __launch_bounds__(RT_THREADS) void routing_k(const uchar* __restrict__ votes,
                                                        const float* __restrict__ x,
                                                        float* __restrict__ out) {
    __shared__ float afs[NI];
    __shared__ float sred[RT_WAVES * CQ];   // 16 KB, [group][q*32+c]
    __shared__ float vj[CQ];                // [q*32+c]
    __shared__ float aout_s[NC];

    int n = blockIdx.x;
    int t = threadIdx.x;
    int wv = t >> 6;      // 0..7
    int l = t & 63;
    int c = l & 31;
    int g = l >> 5;

    if (t < NI) {
        int j = (t >> 5) * CH + 512 + (t & 31);
        float v = gather_x(x, n, j);
        float a = fminf(fmaxf(v, 1e-4f), 1.0f);
        afs[t] = a / (a + EPSV);
    }
    __syncthreads();

    const uchar* vb = votes + (size_t)n * NI * 512;
    v2f vjr2[8];    // cumulative vj pairs, PRE-SCALED by 1/32
    v2f sreg2[8];

#define VROW(S) (((const uint4*)(vb + ((size_t)(((((S) << 3) + wv) << 1) + g) << 9)))[c])

    for (int iter = 0; iter < 3; ++iter) {
#pragma unroll
        for (int j = 0; j < 8; ++j) sreg2[j] = (v2f){0.f, 0.f};

        uint4 f0 = VROW(0), f1 = VROW(1), f2 = VROW(2), f3 = VROW(3);

#pragma clang loop unroll_count(2)
        for (int s = 0; s < 18; ++s) {
            int i = ((s << 3) + wv) * 2 + g;
            uint4 cur = f0;
            f0 = f1; f1 = f2; f2 = f3;
            if (s + 4 < 18) f3 = VROW(s + 4);

            v2f vt2[8];   // raw fp8-decoded pairs (x32-scaled votes)
            vt2[0] = __builtin_amdgcn_cvt_pk_f32_fp8(cur.x, false);
            vt2[1] = __builtin_amdgcn_cvt_pk_f32_fp8(cur.x, true);
            vt2[2] = __builtin_amdgcn_cvt_pk_f32_fp8(cur.y, false);
            vt2[3] = __builtin_amdgcn_cvt_pk_f32_fp8(cur.y, true);
            vt2[4] = __builtin_amdgcn_cvt_pk_f32_fp8(cur.z, false);
            vt2[5] = __builtin_amdgcn_cvt_pk_f32_fp8(cur.z, true);
            vt2[6] = __builtin_amdgcn_cvt_pk_f32_fp8(cur.w, false);
            vt2[7] = __builtin_amdgcn_cvt_pk_f32_fp8(cur.w, true);

            float cij;
            if (iter == 0) {
                cij = afs[i] * (1.0f / 32.0f);
            } else {
                v2f acc2 = {0.f, 0.f};   // vt(raw) . vjr(pre-scaled) == true dot
#pragma unroll
                for (int j = 0; j < 8; ++j) acc2 = pk_fma(vt2[j], vjr2[j], acc2);
                float ah = acc2[0] + acc2[1];
                float e = __expf(ah);
                float ssum = e;
                ssum += __shfl_xor(ssum, 1);
                ssum += __shfl_xor(ssum, 2);
                ssum += __shfl_xor(ssum, 4);
                ssum += __shfl_xor(ssum, 8);
                ssum += __shfl_xor(ssum, 16);
                cij = e * __builtin_amdgcn_rcpf(ssum) * afs[i];
            }
            v2f cij2 = {cij, cij};
#pragma unroll
            for (int j = 0; j < 8; ++j) sreg2[j] = pk_fma(cij2, vt2[j], sreg2[j]);
        }

        // fold g-halves, write 8 partial groups (layout [q*32+c]: bank==c)
#pragma unroll
        for (int j = 0; j < 8; ++j) {
            v2f o;
            o[0] = __shfl_xor(sreg2[j][0], 32);
            o[1] = __shfl_xor(sreg2[j][1], 32);
            sreg2[j] += o;
        }
        if (g == 0) {
            float* sw = &sred[wv * CQ + c];
#pragma unroll
            for (int j = 0; j < 8; ++j) {
                sw[(2 * j) * 32] = sreg2[j][0];
                sw[(2 * j + 1) * 32] = sreg2[j][1];
            }
        }
        __syncthreads();
        {
            float ssum = 0.f;   // 512 threads == CQ columns
#pragma unroll
            for (int k = 0; k < RT_WAVES; ++k) ssum += sred[k * CQ + t];
            sred[t] = ssum * VINV;   // descale the x32 fp8 encoding ONCE
        }
        __syncthreads();

        // squash (threads 0..31, one c each; element (c,q) at sred[q*32+c])
        if (t < NC) {
            float s2 = 0.f;
#pragma unroll
            for (int q = 0; q < 16; ++q) {
                float s = sred[q * 32 + t];
                s2 += s * s;
            }
            float f = (s2 / (1.f + s2)) / sqrtf(s2 + EPSV);
            float vn2 = 0.f;
#pragma unroll
            for (int q = 0; q < 16; ++q) {
                float v = f * sred[q * 32 + t];
                vj[q * 32 + t] = v;
                vn2 += v * v;
            }
            if (iter == 2) {
                float ao = sqrtf(vn2 + EPSV);
                ao = fminf(fmaxf(ao, 1e-4f), 1.f - 1e-4f);
                aout_s[t] = ao;
            }
        }
        __syncthreads();
        if (iter < 2) {
#pragma unroll
            for (int j = 0; j < 8; ++j) {
                v2f nv;
                nv[0] = vj[(2 * j) * 32 + c] * VINV;       // pre-scale for raw dot
                nv[1] = vj[(2 * j + 1) * 32 + c] * VINV;
                vjr2[j] = (iter == 0) ? nv : vjr2[j] + nv;
            }
        }
    }

    // outputs: p_out, a_out, concat(out).  canonical idx t: c=t>>4, q=t&15
    {
        float v = vj[(t & 15) * 32 + (t >> 4)];
        out[(size_t)n * CQ + t] = v;
        out[OFF_CAT + (size_t)n * 544 + t] = v;
    }
    if (t < NC) {
        float ao = aout_s[t];
        out[OFF_AOUT + n * 32 + t] = ao;
        out[OFF_CAT + (size_t)n * 544 + 512 + t] = ao;
    }
}

// ---------------------------------------------------------------------------
extern "C" void kernel_launch(void* const* d_in, const int* in_sizes, int n_in,
                              void* d_out, int out_size, void* d_ws, size_t ws_size,
                              hipStream_t stream) {
    const float* x = (const float*)d_in[0];
    const float* wts = (const float*)d_in[1];
    float* out = (float*)d_out;
    uchar* votes = (uchar*)d_ws;   // 57.8 MB fp8
    _Float16* p16 = (_Float16*)((uchar*)d_ws + P16_OFF);   // 3.6 MB f16

    hipLaunchKernelGGL(prep_k, dim3((NP16 + 255) / 256), dim3(256), 0, stream,
                       x, p16);
    hipLaunchKernelGGL(votes_k, dim3(7, NI), dim3(256), 0, stream,
                       wts, p16, votes);
    hipLaunchKernelGGL(routing_k, dim3(NB), dim3(RT_THREADS), 0, stream,
                       votes, x, out);
}

// Round 11
// 114.508 us; speedup vs baseline: 1.0666x; 1.0365x over previous
//
#include <hip/hip_runtime.h>
#include <hip/hip_fp16.h>
#include <math.h>

// Problem constants
#define NB 392      // n = b*oh*ow = 2*14*14
#define NI 288      // K*K*B = 9*32
#define NC 32       // C
#define NQ 16       // PSIZE
#define CQ 512      // NC*NQ
#define CH 544      // B*(PSIZE+1)
#define EPSV 1e-6f

// votes are fp8 e4m3 scaled by 32; scale folded into staged f16 weights
// (32 = 2^5, exact in f16 -> bitwise-identical products vs scaling after).
#define VSCALE 32.0f
#define VINV (1.0f / 32.0f)

// out layout (floats)
#define OFF_AOUT 200704       // NB*CQ
#define OFF_CAT  213248       // OFF_AOUT + NB*NC

#define RT_THREADS 512
#define RT_WAVES 8

#define TPITCH 68             // uint pitch for the 64x64-uint half-tile (pad 4)

typedef _Float16 v4h __attribute__((ext_vector_type(4)));
typedef float v4f __attribute__((ext_vector_type(4)));
typedef float v2f __attribute__((ext_vector_type(2)));

// dual-f32 FMA (VOP3P); round-8 measured win, kept VERBATIM (incl. volatile —
// round 9 showed perturbing the scheduler here regresses).
__device__ __forceinline__ v2f pk_fma(v2f a, v2f b, v2f c) {
    v2f d;
    asm volatile("v_pk_fma_f32 %0, %1, %2, %3" : "=v"(d) : "v"(a), "v"(b), "v"(c));
    return d;
}

// ---------------------------------------------------------------------------
// Gather from x via the unfold channel-major reinterpret.
__device__ __forceinline__ float gather_x(const float* __restrict__ x, int n, int j) {
    int c_idx = j / 9;
    int rem = j - c_idx * 9;
    int ki = rem / 3;
    int kj = rem - ki * 3;
    int b_ = n / 196;
    int rest = n - b_ * 196;
    int yy = rest / 14;
    int xx = rest - yy * 14;
    int iy = yy + ki - 1;
    int ix = xx + kj - 1;
    float v = 0.f;
    if ((unsigned)iy < 14u && (unsigned)ix < 14u)
        v = x[((b_ * 14 + iy) * 14 + ix) * CH + c_idx];
    return v;
}

// ---------------------------------------------------------------------------
// votes via swapped-operand mfma 16x16x16 f16 (round-3/8 structure).
// ROUND-11 delta (only change vs round 8): ch-chunks 4 -> 2 (16 ct each).
// Barriers 8 -> 4 per block; store runs 128 B -> 256 B contiguous per row.
// LDS 16 KB wlds + 17.4 KB tile = 33.4 KB -> 4 blocks/CU resident (was 6).
// Same values, same vote layout -> absmax bit-identical.
__global__ __launch_bounds__(256) void votes_k(const float* __restrict__ x,
                                               const float* __restrict__ wts,
                                               uchar* __restrict__ votes) {
    __shared__ _Float16 wlds[8192];       // 16 KB swizzled f16 weights (x32)
    __shared__ uint tile[64 * TPITCH];    // 17.4 KB, 64 rows x 64 uints + pad
    int mtt = blockIdx.x;         // 0..6
    int i = blockIdx.y;           // 0..287
    int t = threadIdx.x;
    int wv = t >> 6;
    int l = t & 63;
    int col = l & 15;
    int quad = l >> 4;

    // ---- stage wts[i] -> LDS (f16, x32, transposed, swizzled) ----
    const float* wsrc = wts + (size_t)i * 8192;
#pragma unroll
    for (int k = 0; k < 8; ++k) {
        int f0 = k * 1024 + t * 4;
        float4 w4 = *(const float4*)(wsrc + f0);
        int ct = f0 >> 8;
        int p = (f0 >> 4) & 15;
        int qd = p >> 2;
        int kk = p & 3;
        int q0 = f0 & 15;
        int s = (ct * 4 + qd) & 15;
        int base = ct * 256 + qd * 64 + kk;
        wlds[base + (((q0 + 0) ^ s) << 2)] = (_Float16)(w4.x * VSCALE);
        wlds[base + (((q0 + 1) ^ s) << 2)] = (_Float16)(w4.y * VSCALE);
        wlds[base + (((q0 + 2) ^ s) << 2)] = (_Float16)(w4.z * VSCALE);
        wlds[base + (((q0 + 3) ^ s) << 2)] = (_Float16)(w4.w * VSCALE);
    }

    // A-side p-frag: gather 4 p-values from x in-lane (n_row = col-mapped)
    int n_row = mtt * 64 + wv * 16 + col;
    v4h av = {};
    if (n_row < NB) {
        int jb = (i >> 5) * CH + (i & 31) * 16 + quad * 4;
#pragma unroll
        for (int kk = 0; kk < 4; ++kk)
            av[kk] = (_Float16)gather_x(x, n_row, jb + kk);
    }
    __syncthreads();

    const uchar* tileb = (const uchar*)tile;

    for (int ch = 0; ch < 2; ++ch) {
#pragma unroll
        for (int c8 = 0; c8 < 16; ++c8) {
            int ct = ch * 16 + c8;
            // bv: one conflict-free ds_read_b64 (weights pre-scaled x32)
            v4h bv = *(const v4h*)&wlds[ct * 256 + quad * 64 +
                                        ((col ^ ((ct * 4 + quad) & 15)) << 2)];
            v4f acc = {0.f, 0.f, 0.f, 0.f};
            acc = __builtin_amdgcn_mfma_f32_16x16x16f16(bv, av, acc, 0, 0, 0);
            // lane holds votes[n=...+col][cq = ct*16 + quad*4 + 0..3]
            uint u = __builtin_amdgcn_cvt_pk_fp8_f32(acc[0], acc[1], 0, false);
            u = __builtin_amdgcn_cvt_pk_fp8_f32(acc[2], acc[3], u, true);
            // bank = (4*col + 4*c8 + quad) & 31 -> 2 lanes/bank, free
            tile[(wv * 16 + col) * TPITCH + c8 * 4 + quad] = u;
        }
        __syncthreads();
        // 64 rows x 16 uint4 = 1024 uint4; 4 steps; 16 lanes store a row's 256 B.
#pragma unroll
        for (int k = 0; k < 4; ++k) {
            int idx = k * 256 + t;
            int row = idx >> 4;
            int off = idx & 15;
            int n_out = mtt * 64 + row;
            if (n_out < NB) {
                uint4 d = *(const uint4*)&tileb[row * (TPITCH * 4) + off * 16];
                *(uint4*)(votes + (((size_t)n_out * NI + i) << 9) + ch * 256 + off * 16) = d;
            }
        }
        __syncthreads();
    }
}

// ---------------------------------------------------------------------------
// Fused dynamic routing — ROUND-8 form VERBATIM (best measured, 113.1 total:
// packed-f32 inner math, 18 steps, depth-4 prefetch, 8 waves, one n/block).
__global__ __launch_bounds__(RT_THREADS) void routing_k(const uchar* __restrict__ votes,
                                                        const float* __restrict__ x,
                                                        float* __restrict__ out) {
    __shared__ float afs[NI];
    __shared__ float sred[RT_WAVES * CQ];   // 16 KB, [group][q*32+c]
    __shared__ float vj[CQ];                // [q*32+c]
    __shared__ float aout_s[NC];

    int n = blockIdx.x;
    int t = threadIdx.x;
    int wv = t >> 6;      // 0..7
    int l = t & 63;
    int c = l & 31;
    int g = l >> 5;

    if (t < NI) {
        int j = (t >> 5) * CH + 512 + (t & 31);
        float v = gather_x(x, n, j);
        float a = fminf(fmaxf(v, 1e-4f), 1.0f);
        afs[t] = a / (a + EPSV);
    }
    __syncthreads();

    const uchar* vb = votes + (size_t)n * NI * 512;
    v2f vjr2[8];    // cumulative vj pairs, PRE-SCALED by 1/32
    v2f sreg2[8];

#define VROW(S) (((const uint4*)(vb + ((size_t)(((((S) << 3) + wv) << 1) + g) << 9)))[c])

    for (int iter = 0; iter < 3; ++iter) {
#pragma unroll
        for (int j = 0; j < 8; ++j) sreg2[j] = (v2f){0.f, 0.f};

        uint4 f0 = VROW(0), f1 = VROW(1), f2 = VROW(2), f3 = VROW(3);

#pragma clang loop unroll_count(2)
        for (int s = 0; s < 18; ++s) {
            int i = ((s << 3) + wv) * 2 + g;
            uint4 cur = f0;
            f0 = f1; f1 = f2; f2 = f3;
            if (s + 4 < 18) f3 = VROW(s + 4);

            v2f vt2[8];   // raw fp8-decoded pairs (x32-scaled votes)
            vt2[0] = __builtin_amdgcn_cvt_pk_f32_fp8(cur.x, false);
            vt2[1] = __builtin_amdgcn_cvt_pk_f32_fp8(cur.x, true);
            vt2[2] = __builtin_amdgcn_cvt_pk_f32_fp8(cur.y, false);
            vt2[3] = __builtin_amdgcn_cvt_pk_f32_fp8(cur.y, true);
            vt2[4] = __builtin_amdgcn_cvt_pk_f32_fp8(cur.z, false);
            vt2[5] = __builtin_amdgcn_cvt_pk_f32_fp8(cur.z, true);
            vt2[6] = __builtin_amdgcn_cvt_pk_f32_fp8(cur.w, false);
            vt2[7] = __builtin_amdgcn_cvt_pk_f32_fp8(cur.w, true);

            float cij;
            if (iter == 0) {
                cij = afs[i] * (1.0f / 32.0f);
            } else {
                v2f acc2 = {0.f, 0.f};   // vt(raw) . vjr(pre-scaled) == true dot
#pragma unroll
                for (int j = 0; j < 8; ++j) acc2 = pk_fma(vt2[j], vjr2[j], acc2);
                float ah = acc2[0] + acc2[1];
                float e = __expf(ah);
                float ssum = e;
                ssum += __shfl_xor(ssum, 1);
                ssum += __shfl_xor(ssum, 2);
                ssum += __shfl_xor(ssum, 4);
                ssum += __shfl_xor(ssum, 8);
                ssum += __shfl_xor(ssum, 16);
                cij = e * __builtin_amdgcn_rcpf(ssum) * afs[i];
            }
            v2f cij2 = {cij, cij};
#pragma unroll
            for (int j = 0; j < 8; ++j) sreg2[j] = pk_fma(cij2, vt2[j], sreg2[j]);
        }

        // fold g-halves, write 8 partial groups (layout [q*32+c]: bank==c)
#pragma unroll
        for (int j = 0; j < 8; ++j) {
            v2f o;
            o[0] = __shfl_xor(sreg2[j][0], 32);
            o[1] = __shfl_xor(sreg2[j][1], 32);
            sreg2[j] += o;
        }
        if (g == 0) {
            float* sw = &sred[wv * CQ + c];
#pragma unroll
            for (int j = 0; j < 8; ++j) {
                sw[(2 * j) * 32] = sreg2[j][0];
                sw[(2 * j + 1) * 32] = sreg2[j][1];
            }
        }
        __syncthreads();
        {
            float ssum = 0.f;   // 512 threads == CQ columns
#pragma unroll
            for (int k = 0; k < RT_WAVES; ++k) ssum += sred[k * CQ + t];
            sred[t] = ssum * VINV;   // descale the x32 fp8 encoding ONCE
        }
        __syncthreads();

        // squash (threads 0..31, one c each; element (c,q) at sred[q*32+c])
        if (t < NC) {
            float s2 = 0.f;
#pragma unroll
            for (int q = 0; q < 16; ++q) {
                float s = sred[q * 32 + t];
                s2 += s * s;
            }
            float f = (s2 / (1.f + s2)) / sqrtf(s2 + EPSV);
            float vn2 = 0.f;
#pragma unroll
            for (int q = 0; q < 16; ++q) {
                float v = f * sred[q * 32 + t];
                vj[q * 32 + t] = v;
                vn2 += v * v;
            }
            if (iter == 2) {
                float ao = sqrtf(vn2 + EPSV);
                ao = fminf(fmaxf(ao, 1e-4f), 1.f - 1e-4f);
                aout_s[t] = ao;
            }
        }
        __syncthreads();
        if (iter < 2) {
#pragma unroll
            for (int j = 0; j < 8; ++j) {
                v2f nv;
                nv[0] = vj[(2 * j) * 32 + c] * VINV;       // pre-scale for raw dot
                nv[1] = vj[(2 * j + 1) * 32 + c] * VINV;
                vjr2[j] = (iter == 0) ? nv : vjr2[j] + nv;
            }
        }
    }

    // outputs: p_out, a_out, concat(out).  canonical idx t: c=t>>4, q=t&15
    {
        float v = vj[(t & 15) * 32 + (t >> 4)];
        out[(size_t)n * CQ + t] = v;
        out[OFF_CAT + (size_t)n * 544 + t] = v;
    }
    if (t < NC) {
        float ao = aout_s[t];
        out[OFF_AOUT + n * 32 + t] = ao;
        out[OFF_CAT + (size_t)n * 544 + 512 + t] = ao;
    }
}

// ---------------------------------------------------------------------------
extern "C" void kernel_launch(void* const* d_in, const int* in_sizes, int n_in,
                              void* d_out, int out_size, void* d_ws, size_t ws_size,
                              hipStream_t stream) {
    const float* x = (const float*)d_in[0];
    const float* wts = (const float*)d_in[1];
    float* out = (float*)d_out;
    uchar* votes = (uchar*)d_ws;   // 57.8 MB fp8

    hipLaunchKernelGGL(votes_k, dim3(7, NI), dim3(256), 0, stream,
                       x, wts, votes);
    hipLaunchKernelGGL(routing_k, dim3(NB), dim3(RT_THREADS), 0, stream,
                       votes, x, out);
}

// Round 12
// 112.525 us; speedup vs baseline: 1.0854x; 1.0176x over previous
//
#include <hip/hip_runtime.h>
#include <hip/hip_fp16.h>
#include <math.h>

// =============================================================================
// FINAL KERNEL (round-8 configuration, best measured: 113.1 us).
// Session ledger:
//  - votes_k ~22 us (measured via grid-z duplication, round 6): mfma f16
//    swapped-operand, LDS-staged swizzled weights, fp8 e4m3 x32 vote tensor.
//  - routing_k ~30 us (measured via grid-y duplication, round 7): VALUBusy 44%,
//    VGPR 64, zero bank conflicts -> dependency-latency-bound, not issue-bound.
//  - Harness-owned ~60 us: 256 MiB workspace poison fill (42.5 us @ 80% HBM
//    peak) + memsets + graph gaps. Unremovable from kernel side.
// Failed/neutral levers (measured): routing LDS vote-stash (-occupancy, +9),
// 16-wave split (0), cooperative & hand-rolled grid-sync fusion (fail/+160),
// ILP-2 routing (+9 regress), pre-gathered A-side (+5 regress), barrier
// halving (+1.4 regress), pk_fma packing (-1.4 WIN, kept).
// =============================================================================

// Problem constants
#define NB 392      // n = b*oh*ow = 2*14*14
#define NI 288      // K*K*B = 9*32
#define NC 32       // C
#define NQ 16       // PSIZE
#define CQ 512      // NC*NQ
#define CH 544      // B*(PSIZE+1)
#define EPSV 1e-6f

// votes are fp8 e4m3 scaled by 32; scale folded into staged f16 weights
// (32 = 2^5, exact in f16 -> bitwise-identical products vs scaling after).
#define VSCALE 32.0f
#define VINV (1.0f / 32.0f)

// out layout (floats)
#define OFF_AOUT 200704       // NB*CQ
#define OFF_CAT  213248       // OFF_AOUT + NB*NC

#define RT_THREADS 512
#define RT_WAVES 8

typedef _Float16 v4h __attribute__((ext_vector_type(4)));
typedef float v4f __attribute__((ext_vector_type(4)));
typedef float v2f __attribute__((ext_vector_type(2)));

// dual-f32 FMA (VOP3P); round-8 measured win (-1.4 us), kept verbatim.
__device__ __forceinline__ v2f pk_fma(v2f a, v2f b, v2f c) {
    v2f d;
    asm volatile("v_pk_fma_f32 %0, %1, %2, %3" : "=v"(d) : "v"(a), "v"(b), "v"(c));
    return d;
}

// ---------------------------------------------------------------------------
// Gather from x via the unfold channel-major reinterpret.
__device__ __forceinline__ float gather_x(const float* __restrict__ x, int n, int j) {
    int c_idx = j / 9;
    int rem = j - c_idx * 9;
    int ki = rem / 3;
    int kj = rem - ki * 3;
    int b_ = n / 196;
    int rest = n - b_ * 196;
    int yy = rest / 14;
    int xx = rest - yy * 14;
    int iy = yy + ki - 1;
    int ix = xx + kj - 1;
    float v = 0.f;
    if ((unsigned)iy < 14u && (unsigned)ix < 14u)
        v = x[((b_ * 14 + iy) * 14 + ix) * CH + c_idx];
    return v;
}

// ---------------------------------------------------------------------------
// votes via swapped-operand mfma 16x16x16 f16 (round-3 structure, ~22 us).
__global__ __launch_bounds__(256) void votes_k(const float* __restrict__ x,
                                               const float* __restrict__ wts,
                                               uchar* __restrict__ votes) {
    __shared__ _Float16 wlds[8192];     // 16 KB swizzled f16 weights (x32)
    __shared__ uint tile[64 * 36];      // 9 KB, pitch 36 dwords (144 B)
    int mtt = blockIdx.x;         // 0..6
    int i = blockIdx.y;           // 0..287
    int t = threadIdx.x;
    int wv = t >> 6;
    int l = t & 63;
    int col = l & 15;
    int quad = l >> 4;

    // ---- stage wts[i] -> LDS (f16, x32, transposed, swizzled) ----
    const float* wsrc = wts + (size_t)i * 8192;
#pragma unroll
    for (int k = 0; k < 8; ++k) {
        int f0 = k * 1024 + t * 4;
        float4 w4 = *(const float4*)(wsrc + f0);
        int ct = f0 >> 8;
        int p = (f0 >> 4) & 15;
        int qd = p >> 2;
        int kk = p & 3;
        int q0 = f0 & 15;
        int s = (ct * 4 + qd) & 15;
        int base = ct * 256 + qd * 64 + kk;
        wlds[base + (((q0 + 0) ^ s) << 2)] = (_Float16)(w4.x * VSCALE);
        wlds[base + (((q0 + 1) ^ s) << 2)] = (_Float16)(w4.y * VSCALE);
        wlds[base + (((q0 + 2) ^ s) << 2)] = (_Float16)(w4.z * VSCALE);
        wlds[base + (((q0 + 3) ^ s) << 2)] = (_Float16)(w4.w * VSCALE);
    }

    // A-side p-frag: gather 4 p-values from x in-lane (n_row = col-mapped)
    int n_row = mtt * 64 + wv * 16 + col;
    v4h av = {};
    if (n_row < NB) {
        int jb = (i >> 5) * CH + (i & 31) * 16 + quad * 4;
#pragma unroll
        for (int kk = 0; kk < 4; ++kk)
            av[kk] = (_Float16)gather_x(x, n_row, jb + kk);
    }
    __syncthreads();

    const uchar* tileb = (const uchar*)tile;

    for (int ch = 0; ch < 4; ++ch) {
#pragma unroll
        for (int c8 = 0; c8 < 8; ++c8) {
            int ct = ch * 8 + c8;
            // bv: one conflict-free ds_read_b64 (weights pre-scaled x32)
            v4h bv = *(const v4h*)&wlds[ct * 256 + quad * 64 +
                                        ((col ^ ((ct * 4 + quad) & 15)) << 2)];
            v4f acc = {0.f, 0.f, 0.f, 0.f};
            acc = __builtin_amdgcn_mfma_f32_16x16x16f16(bv, av, acc, 0, 0, 0);
            // lane holds votes[n=...+col][cq = ct*16 + quad*4 + 0..3]
            uint u = __builtin_amdgcn_cvt_pk_fp8_f32(acc[0], acc[1], 0, false);
            u = __builtin_amdgcn_cvt_pk_fp8_f32(acc[2], acc[3], u, true);
            tile[(wv * 16 + col) * 36 + c8 * 4 + quad] = u;
        }
        __syncthreads();
        // 64 rows x 8 uint4 = 512 uint4; 2 steps; 8 lanes store a row's 128 B.
#pragma unroll
        for (int k = 0; k < 2; ++k) {
            int idx = k * 256 + t;
            int row = idx >> 3;
            int off = idx & 7;
            int n_out = mtt * 64 + row;
            if (n_out < NB) {
                uint4 d = *(const uint4*)&tileb[row * 144 + off * 16];
                *(uint4*)(votes + (((size_t)n_out * NI + i) << 9) + ch * 128 + off * 16) = d;
            }
        }
        __syncthreads();
    }
}

// ---------------------------------------------------------------------------
// Fused dynamic routing — round-8 form verbatim (~30 us): packed-f32 inner
// math, 18 steps, depth-4 prefetch, 8 waves, one n per block.
__global__ __launch_bounds__(RT_THREADS) void routing_k(const uchar* __restrict__ votes,
                                                        const float* __restrict__ x,
                                                        float* __restrict__ out) {
    __shared__ float afs[NI];
    __shared__ float sred[RT_WAVES * CQ];   // 16 KB, [group][q*32+c]
    __shared__ float vj[CQ];                // [q*32+c]
    __shared__ float aout_s[NC];

    int n = blockIdx.x;
    int t = threadIdx.x;
    int wv = t >> 6;      // 0..7
    int l = t & 63;
    int c = l & 31;
    int g = l >> 5;

    if (t < NI) {
        int j = (t >> 5) * CH + 512 + (t & 31);
        float v = gather_x(x, n, j);
        float a = fminf(fmaxf(v, 1e-4f), 1.0f);
        afs[t] = a / (a + EPSV);
    }
    __syncthreads();

    const uchar* vb = votes + (size_t)n * NI * 512;
    v2f vjr2[8];    // cumulative vj pairs, PRE-SCALED by 1/32
    v2f sreg2[8];

#define VROW(S) (((const uint4*)(vb + ((size_t)(((((S) << 3) + wv) << 1) + g) << 9)))[c])

    for (int iter = 0; iter < 3; ++iter) {
#pragma unroll
        for (int j = 0; j < 8; ++j) sreg2[j] = (v2f){0.f, 0.f};

        uint4 f0 = VROW(0), f1 = VROW(1), f2 = VROW(2), f3 = VROW(3);

#pragma clang loop unroll_count(2)
        for (int s = 0; s < 18; ++s) {
            int i = ((s << 3) + wv) * 2 + g;
            uint4 cur = f0;
            f0 = f1; f1 = f2; f2 = f3;
            if (s + 4 < 18) f3 = VROW(s + 4);

            v2f vt2[8];   // raw fp8-decoded pairs (x32-scaled votes)
            vt2[0] = __builtin_amdgcn_cvt_pk_f32_fp8(cur.x, false);
            vt2[1] = __builtin_amdgcn_cvt_pk_f32_fp8(cur.x, true);
            vt2[2] = __builtin_amdgcn_cvt_pk_f32_fp8(cur.y, false);
            vt2[3] = __builtin_amdgcn_cvt_pk_f32_fp8(cur.y, true);
            vt2[4] = __builtin_amdgcn_cvt_pk_f32_fp8(cur.z, false);
            vt2[5] = __builtin_amdgcn_cvt_pk_f32_fp8(cur.z, true);
            vt2[6] = __builtin_amdgcn_cvt_pk_f32_fp8(cur.w, false);
            vt2[7] = __builtin_amdgcn_cvt_pk_f32_fp8(cur.w, true);

            float cij;
            if (iter == 0) {
                cij = afs[i] * (1.0f / 32.0f);
            } else {
                v2f acc2 = {0.f, 0.f};   // vt(raw) . vjr(pre-scaled) == true dot
#pragma unroll
                for (int j = 0; j < 8; ++j) acc2 = pk_fma(vt2[j], vjr2[j], acc2);
                float ah = acc2[0] + acc2[1];
                float e = __expf(ah);
                float ssum = e;
                ssum += __shfl_xor(ssum, 1);
                ssum += __shfl_xor(ssum, 2);
                ssum += __shfl_xor(ssum, 4);
                ssum += __shfl_xor(ssum, 8);
                ssum += __shfl_xor(ssum, 16);
                cij = e * __builtin_amdgcn_rcpf(ssum) * afs[i];
            }
            v2f cij2 = {cij, cij};
#pragma unroll
            for (int j = 0; j < 8; ++j) sreg2[j] = pk_fma(cij2, vt2[j], sreg2[j]);
        }

        // fold g-halves, write 8 partial groups (layout [q*32+c]: bank==c)
#pragma unroll
        for (int j = 0; j < 8; ++j) {
            v2f o;
            o[0] = __shfl_xor(sreg2[j][0], 32);
            o[1] = __shfl_xor(sreg2[j][1], 32);
            sreg2[j] += o;
        }
        if (g == 0) {
            float* sw = &sred[wv * CQ + c];
#pragma unroll
            for (int j = 0; j < 8; ++j) {
                sw[(2 * j) * 32] = sreg2[j][0];
                sw[(2 * j + 1) * 32] = sreg2[j][1];
            }
        }
        __syncthreads();
        {
            float ssum = 0.f;   // 512 threads == CQ columns
#pragma unroll
            for (int k = 0; k < RT_WAVES; ++k) ssum += sred[k * CQ + t];
            sred[t] = ssum * VINV;   // descale the x32 fp8 encoding ONCE
        }
        __syncthreads();

        // squash (threads 0..31, one c each; element (c,q) at sred[q*32+c])
        if (t < NC) {
            float s2 = 0.f;
#pragma unroll
            for (int q = 0; q < 16; ++q) {
                float s = sred[q * 32 + t];
                s2 += s * s;
            }
            float f = (s2 / (1.f + s2)) / sqrtf(s2 + EPSV);
            float vn2 = 0.f;
#pragma unroll
            for (int q = 0; q < 16; ++q) {
                float v = f * sred[q * 32 + t];
                vj[q * 32 + t] = v;
                vn2 += v * v;
            }
            if (iter == 2) {
                float ao = sqrtf(vn2 + EPSV);
                ao = fminf(fmaxf(ao, 1e-4f), 1.f - 1e-4f);
                aout_s[t] = ao;
            }
        }
        __syncthreads();
        if (iter < 2) {
#pragma unroll
            for (int j = 0; j < 8; ++j) {
                v2f nv;
                nv[0] = vj[(2 * j) * 32 + c] * VINV;       // pre-scale for raw dot
                nv[1] = vj[(2 * j + 1) * 32 + c] * VINV;
                vjr2[j] = (iter == 0) ? nv : vjr2[j] + nv;
            }
        }
    }

    // outputs: p_out, a_out, concat(out).  canonical idx t: c=t>>4, q=t&15
    {
        float v = vj[(t & 15) * 32 + (t >> 4)];
        out[(size_t)n * CQ + t] = v;
        out[OFF_CAT + (size_t)n * 544 + t] = v;
    }
    if (t < NC) {
        float ao = aout_s[t];
        out[OFF_AOUT + n * 32 + t] = ao;
        out[OFF_CAT + (size_t)n * 544 + 512 + t] = ao;
    }
}

// ---------------------------------------------------------------------------
extern "C" void kernel_launch(void* const* d_in, const int* in_sizes, int n_in,
                              void* d_out, int out_size, void* d_ws, size_t ws_size,
                              hipStream_t stream) {
    const float* x = (const float*)d_in[0];
    const float* wts = (const float*)d_in[1];
    float* out = (float*)d_out;
    uchar* votes = (uchar*)d_ws;   // 57.8 MB fp8

    hipLaunchKernelGGL(votes_k, dim3(7, NI), dim3(256), 0, stream,
                       x, wts, votes);
    hipLaunchKernelGGL(routing_k, dim3(NB), dim3(RT_THREADS), 0, stream,
                       votes, x, out);
}